// Round 2
// baseline (46.124 us; speedup 1.0000x reference)
//
#include <hip/hip_runtime.h>

// BlankEmbedding: out[b,s,:] = sum_{m=0..8} c[b,s,m] * emb_table[x[b,s-m], :]
// where c comes from the recurrence out^(k)[s] = out^(k-1)[s] + p[s-k]*out^(k-1)[s-1],
// k = 1..8, p[s] = is_preblank[s] = (x[s+1] < 16) && !(x[s] < 16), zero-filled at edges.

constexpr int S_LEN = 4096;
constexpr int D_DIM = 2048;

typedef float f32x4 __attribute__((ext_vector_type(4)));

__global__ __launch_bounds__(256)
void blank_emb_kernel(const int* __restrict__ x,
                      const float* __restrict__ table,
                      float* __restrict__ out) {
    const int bs = blockIdx.x;                 // b*S + s
    const int s  = bs & (S_LEN - 1);
    const int* xb = x + (bs >> 12) * S_LEN;    // batch row (S_LEN == 4096)

    __shared__ int sh_tok[9];
    __shared__ int sh_c[9];

    if (threadIdx.x == 0) {
        // tokens x[s-m], m = 0..8 (clamped; coefficient is provably 0 for t<0)
        int tok[9];
        int bl[9];
        #pragma unroll
        for (int m = 0; m < 9; ++m) {
            const int t  = s - m;
            const int tv = (t >= 0) ? xb[t] : 2048;   // sentinel: non-blank
            tok[m] = (t >= 0) ? tv : 0;
            bl[m]  = (tv < 16) ? 1 : 0;
        }
        // p[i] = is_preblank at seq index (s - i), i = 1..8
        int p[9];
        p[0] = 0;
        #pragma unroll
        for (int i = 1; i < 9; ++i)
            p[i] = (s - i >= 0 && bl[i - 1] && !bl[i]) ? 1 : 0;

        // Triangular DP: C[j][m] = coeff of e[(s-j)-m] in out^(k)[s-j].
        // Level 0: identity. Level k: C[j][m] += p[j+k] * C[j+1][m-1].
        // In-place valid: j ascending uses C[j+1] still at level k-1.
        int C[9][9];
        #pragma unroll
        for (int j = 0; j < 9; ++j) {
            #pragma unroll
            for (int m = 0; m < 9; ++m) C[j][m] = (m == 0) ? 1 : 0;
        }
        #pragma unroll
        for (int k = 1; k <= 8; ++k) {
            #pragma unroll
            for (int j = 0; j + k <= 8; ++j) {
                const int pv = p[j + k];
                #pragma unroll
                for (int m = 8; m >= 1; --m)
                    C[j][m] += pv * C[j + 1][m - 1];
            }
        }
        #pragma unroll
        for (int m = 0; m < 9; ++m) { sh_tok[m] = tok[m]; sh_c[m] = C[0][m]; }
    }
    __syncthreads();

    // 256 threads x 8 floats (2x float4) = 2048-dim row
    const int d0 = (int)threadIdx.x * 4;
    const int d1 = d0 + 1024;

    const float* row0 = table + (size_t)sh_tok[0] * D_DIM;   // c0 == 1 always
    f32x4 a0 = *(const f32x4*)(row0 + d0);
    f32x4 a1 = *(const f32x4*)(row0 + d1);

    #pragma unroll
    for (int m = 1; m < 9; ++m) {
        const int c = sh_c[m];                 // uniform across block
        if (c != 0) {
            const float fc = (float)c;
            const float* rm = table + (size_t)sh_tok[m] * D_DIM;
            const f32x4 v0 = *(const f32x4*)(rm + d0);
            const f32x4 v1 = *(const f32x4*)(rm + d1);
            a0 += fc * v0;
            a1 += fc * v1;
        }
    }

    float* op = out + (size_t)bs * D_DIM;
    __builtin_nontemporal_store(a0, (f32x4*)(op + d0));
    __builtin_nontemporal_store(a1, (f32x4*)(op + d1));
}

extern "C" void kernel_launch(void* const* d_in, const int* in_sizes, int n_in,
                              void* d_out, int out_size, void* d_ws, size_t ws_size,
                              hipStream_t stream) {
    const int*   x     = (const int*)d_in[0];
    const float* table = (const float*)d_in[1];
    float*       out   = (float*)d_out;

    const int BS = in_sizes[0];                // B * S = 16384
    blank_emb_kernel<<<BS, 256, 0, stream>>>(x, table, out);
}

// Round 3
// 44.415 us; speedup vs baseline: 1.0385x; 1.0385x over previous
//
#include <hip/hip_runtime.h>

// BlankEmbedding: out[b,s,:] = sum_{m=0..8} c[m] * emb_table[x[b,s-m], :]
// c[m] depends only on the 8 preblank bits p[1..8] (p[i] = blank(x[s-i+1]) && !blank(x[s-i])),
// so all coefficient vectors are precomputed into a 256-entry constexpr table,
// packed as 8 bytes (c[m] <= C(8,m) <= 70). c[0] == 1 always.

constexpr int S_LEN = 4096;
constexpr int D_DIM = 2048;

typedef float f32x4 __attribute__((ext_vector_type(4)));

struct CoefTab { unsigned long long v[256]; };

constexpr CoefTab make_tab() {
    CoefTab t{};
    for (int mask = 0; mask < 256; ++mask) {
        int p[9] = {};
        for (int i = 1; i <= 8; ++i) p[i] = (mask >> (i - 1)) & 1;
        // Triangular DP (verified against reference in R2's passing kernel)
        int C[9][9] = {};
        for (int j = 0; j < 9; ++j) C[j][0] = 1;
        for (int k = 1; k <= 8; ++k)
            for (int j = 0; j + k <= 8; ++j)
                for (int m = 8; m >= 1; --m)
                    C[j][m] += p[j + k] * C[j + 1][m - 1];
        unsigned long long pack = 0ULL;
        for (int m = 1; m <= 8; ++m)
            pack |= (unsigned long long)(C[0][m] & 0xff) << ((m - 1) * 8);
        t.v[mask] = pack;
    }
    return t;
}

__device__ __constant__ CoefTab cTab = make_tab();

__global__ __launch_bounds__(256)
void blank_emb_kernel(const int* __restrict__ x,
                      const float* __restrict__ table,
                      float* __restrict__ out) {
    const int bs = blockIdx.x;                 // b*S + s
    const int s  = bs & (S_LEN - 1);
    const int* __restrict__ xb = x + (bs >> 12) * S_LEN;

    // ---- block-uniform scalar phase (no LDS, no barrier) ----
    int tok[9];
    unsigned bl = 0;
    #pragma unroll
    for (int m = 0; m < 9; ++m) {
        const int t  = s - m;
        const int tv = (t >= 0) ? xb[t] : 2048;   // sentinel: non-blank
        tok[m] = (t >= 0) ? tv : 0;               // coeff provably 0 when t<0
        if (tv < 16) bl |= (1u << m);
    }
    // p[i] = bl[i-1] && !bl[i], valid only for i <= s  (i = 1..8 -> bit i-1)
    const unsigned valid = (s >= 8) ? 0xffu : ((1u << s) - 1u);
    const unsigned mask  = bl & ~(bl >> 1) & valid;
    const unsigned long long pk = cTab.v[mask];   // packed c[1..8]

    // ---- vector phase: 256 threads x 8 floats = 2048-dim row ----
    const int d0 = (int)threadIdx.x * 4;
    const int d1 = d0 + 1024;

    const float* __restrict__ row0 = table + (size_t)tok[0] * D_DIM;
    f32x4 a0 = *(const f32x4*)(row0 + d0);
    f32x4 a1 = *(const f32x4*)(row0 + d1);

    if (pk) {                                     // ~94% of positions: pure row copy
        #pragma unroll
        for (int m = 1; m < 9; ++m) {
            const int c = (int)((pk >> ((m - 1) * 8)) & 0xff);
            if (c != 0) {
                const float fc = (float)c;
                const float* __restrict__ rm = table + (size_t)tok[m] * D_DIM;
                a0 += fc * *(const f32x4*)(rm + d0);
                a1 += fc * *(const f32x4*)(rm + d1);
            }
        }
    }

    float* op = out + (size_t)bs * D_DIM;
    __builtin_nontemporal_store(a0, (f32x4*)(op + d0));
    __builtin_nontemporal_store(a1, (f32x4*)(op + d1));
}

extern "C" void kernel_launch(void* const* d_in, const int* in_sizes, int n_in,
                              void* d_out, int out_size, void* d_ws, size_t ws_size,
                              hipStream_t stream) {
    const int*   x     = (const int*)d_in[0];
    const float* table = (const float*)d_in[1];
    float*       out   = (float*)d_out;

    const int BS = in_sizes[0];                // B * S = 16384
    blank_emb_kernel<<<BS, 256, 0, stream>>>(x, table, out);
}